// Round 3
// baseline (169.237 us; speedup 1.0000x reference)
//
#include <hip/hip_runtime.h>

// PairwiseMamba R3: time-split chunked-scan decomposition.
// h_T is linear in h_0, so each sequence's T=2048 steps split into 2 halves
// run by independent blocks (grid 4608x? -> 2x waves/CU vs R2):
//   half 0: h_in = 0, outputs per-state h_end[32] + local reduced (q,sk)
//   half 1: also tracks p = prod(dA), w = sum p_t * C_t * g_t;
//           true q1 = q1_loc + sum_s w[s] * h_end0[s]
// combine kernel: feat[n] = (q0 + q1 + w.h0 reduced with out_proj) / T
// proj kernel: feat -> relu(proj) -> mean over P=36 -> out[8,16,16]
//
// Block = 64 threads (1 wave) = 2 seqs; per 32-step chunk:
//   phase 1: 2 seq x 32 t front-end -> 32-float LDS record (XOR-swizzled slots)
//   phase 2: 2 seq x 32 (d,s) lanes scan 32 steps (dA = exp2(dt*A2) in-lane)

#define T_LEN  2048
#define N_SEQ  4608
#define SPB    2           // sequences per block
#define TC     32          // chunk length
#define TSPLIT 2
#define TH     (T_LEN / TSPLIT)   // 1024 steps per half
#define NCHH   (TH / TC)          // 32 chunks per half
#define LOG2E  1.4426950408889634f
#define LN2    0.6931471805599453f

__device__ __forceinline__ float fexp2(float x){ return __builtin_amdgcn_exp2f(x); }
__device__ __forceinline__ float frcp (float x){ return __builtin_amdgcn_rcpf(x); }
__device__ __forceinline__ float flog2(float x){ return __builtin_amdgcn_logf(x); }
__device__ __forceinline__ float silu_f(float v){ return v * frcp(1.0f + fexp2(v * -LOG2E)); }

__global__ __launch_bounds__(64, 4) void mamba_half_kernel(
    const float* __restrict__ raw,        // [N,2,T]
    const float* __restrict__ in_proj_w,  // [8,2]
    const float* __restrict__ conv_w,     // [4,2]
    const float* __restrict__ conv_b,     // [4]
    const float* __restrict__ x_proj_w,   // [17,4]
    const float* __restrict__ dt_proj_w,  // [4,1]
    const float* __restrict__ dt_proj_b,  // [4]
    const float* __restrict__ A_log,      // [4,8]
    const float* __restrict__ D_skip,     // [4]
    const float* __restrict__ out_proj_w, // [2,4]
    float* __restrict__ H0,               // [N,32] per-state h_end of half 0
    float* __restrict__ W1,               // [N,32] per-state w of half 1
    float* __restrict__ QR)               // [N,2,2] reduced (q+sk) per half
{
    __shared__ __attribute__((aligned(16))) float rec[SPB * TC * 32];   // 8 KiB

    const int j    = threadIdx.x;   // 0..63
    const int seq  = j >> 5;        // 0..1 (both roles)
    const int tt   = j & 31;        // phase-1: time slot in chunk
    const int d2   = (j & 31) >> 3; // phase-2: inner channel
    const int s2   = j & 7;         // phase-2: state
    const int half = blockIdx.y;    // 0 or 1 (uniform)
    const int t0   = half * TH;

    // ---------------- weights in registers ----------------
    float wi[8][2];
#pragma unroll
    for (int r = 0; r < 8; ++r){ wi[r][0] = in_proj_w[r*2]; wi[r][1] = in_proj_w[r*2+1]; }
    float cw0[4], cw1[4], cb[4], dtw[4], dtb[4], op0[4], op1[4], op0D[4], op1D[4];
#pragma unroll
    for (int d = 0; d < 4; ++d){
        cw0[d] = conv_w[d*2]; cw1[d] = conv_w[d*2+1]; cb[d] = conv_b[d];
        dtw[d] = dt_proj_w[d]; dtb[d] = dt_proj_b[d];
        op0[d] = out_proj_w[d]; op1[d] = out_proj_w[4+d];
        float Dk = D_skip[d];
        op0D[d] = op0[d] * Dk; op1D[d] = op1[d] * Dk;
    }
    float xw[17][4];
#pragma unroll
    for (int r = 0; r < 17; ++r)
#pragma unroll
        for (int d = 0; d < 4; ++d) xw[r][d] = x_proj_w[r*4 + d];
    const float A2l = -fexp2(A_log[d2*8 + s2] * LOG2E) * LOG2E;

    const int n = blockIdx.x * SPB + seq;
    const float* u0base = raw + (size_t)n * 2 * T_LEN;
    const float* u1base = u0base + T_LEN;

    // phase-2 LDS float-index tables (compile-time indexed after unroll)
    const int sbase = seq * (TC * 32);
    const int sl_dt = d2 >> 1,        in_dt = (d2 & 1) * 2;
    const int sl_bc = 2 + (s2 >> 1),  in_bc = (s2 & 1) * 2;
    int odt[8], obc[8], og[8];
#pragma unroll
    for (int k2 = 0; k2 < 8; ++k2){
        odt[k2] = sbase + ((sl_dt ^ k2) << 2) + in_dt;
        obc[k2] = sbase + ((sl_bc ^ k2) << 2) + in_bc;
        og [k2] = sbase + ((6     ^ k2) << 2) + d2;
    }

    float h = 0.f, q = 0.f, sk0 = 0.f, sk1 = 0.f;
    float p = 1.f, w = 0.f;

    // preload u for chunk 0 of this half
    const int tg0 = t0 + tt;
    float cu0 = u0base[tg0], cu1 = u1base[tg0];
    float pu0 = (tg0 > 0) ? u0base[tg0-1] : 0.f;
    float pu1 = (tg0 > 0) ? u1base[tg0-1] : 0.f;
    float nu0 = 0.f, nu1 = 0.f, np0 = 0.f, np1 = 0.f;

    for (int c = 0; c < NCHH; ++c){
        // ================= phase 1: front-end =================
        float x[4], g[4];
#pragma unroll
        for (int d = 0; d < 4; ++d){
            float xr = fmaf(cu0, wi[d][0],   cu1 * wi[d][1]);
            float xp = fmaf(pu0, wi[d][0],   pu1 * wi[d][1]);
            float zr = fmaf(cu0, wi[4+d][0], cu1 * wi[4+d][1]);
            float xc = fmaf(xp, cw0[d], fmaf(xr, cw1[d], cb[d]));
            x[d] = silu_f(xc);
            g[d] = silu_f(zr);
        }
        float dtr = 0.f;
#pragma unroll
        for (int d = 0; d < 4; ++d) dtr = fmaf(x[d], xw[0][d], dtr);
        float Bv[8], Cv[8];
#pragma unroll
        for (int s = 0; s < 8; ++s){
            float b  = x[0] * xw[1+s][0];
            float cc = x[0] * xw[9+s][0];
#pragma unroll
            for (int d = 1; d < 4; ++d){
                b  = fmaf(x[d], xw[1+s][d], b);
                cc = fmaf(x[d], xw[9+s][d], cc);
            }
            Bv[s] = b; Cv[s] = cc;
        }
        float dt[4], dtx[4];
#pragma unroll
        for (int d = 0; d < 4; ++d){
            float v = fmaf(dtr, dtw[d], dtb[d]);
            dt[d]  = LN2 * flog2(1.0f + fexp2(v * LOG2E));   // softplus
            dtx[d] = dt[d] * x[d];
        }
#pragma unroll
        for (int d = 0; d < 4; ++d){
            float gx = g[d] * x[d];
            sk0 = fmaf(gx, op0D[d], sk0);
            sk1 = fmaf(gx, op1D[d], sk1);
        }
        {
            const int rb = seq*(TC*32) + tt*32;
            const int tk = tt & 7;
            *(float4*)&rec[rb + ((0^tk)<<2)] = make_float4(dt[0], dtx[0], dt[1], dtx[1]);
            *(float4*)&rec[rb + ((1^tk)<<2)] = make_float4(dt[2], dtx[2], dt[3], dtx[3]);
            *(float4*)&rec[rb + ((2^tk)<<2)] = make_float4(Bv[0], Cv[0], Bv[1], Cv[1]);
            *(float4*)&rec[rb + ((3^tk)<<2)] = make_float4(Bv[2], Cv[2], Bv[3], Cv[3]);
            *(float4*)&rec[rb + ((4^tk)<<2)] = make_float4(Bv[4], Cv[4], Bv[5], Cv[5]);
            *(float4*)&rec[rb + ((5^tk)<<2)] = make_float4(Bv[6], Cv[6], Bv[7], Cv[7]);
            *(float4*)&rec[rb + ((6^tk)<<2)] = make_float4(g[0], g[1], g[2], g[3]);
        }
        __syncthreads();

        // prefetch u for next chunk (hides HBM latency under phase 2)
        if (c + 1 < NCHH){
            const int t = t0 + (c+1)*TC + tt;
            nu0 = u0base[t];   nu1 = u1base[t];
            np0 = u0base[t-1]; np1 = u1base[t-1];
        }

        // ================= phase 2: scan TC steps =================
        if (half == 0){
#pragma unroll
            for (int st = 0; st < TC; ++st){
                const int k2 = st & 7;
                const int tb = st * 32;
                const float2 ddx = *(const float2*)&rec[tb + odt[k2]];
                const float2 bc  = *(const float2*)&rec[tb + obc[k2]];
                const float  gt  = rec[tb + og[k2]];
                const float dA = fexp2(ddx.x * A2l);
                h = fmaf(dA, h, ddx.y * bc.x);
                q = fmaf(h, bc.y * gt, q);
            }
        } else {
#pragma unroll
            for (int st = 0; st < TC; ++st){
                const int k2 = st & 7;
                const int tb = st * 32;
                const float2 ddx = *(const float2*)&rec[tb + odt[k2]];
                const float2 bc  = *(const float2*)&rec[tb + obc[k2]];
                const float  gt  = rec[tb + og[k2]];
                const float dA = fexp2(ddx.x * A2l);
                const float cg = bc.y * gt;
                h = fmaf(dA, h, ddx.y * bc.x);
                q = fmaf(h, cg, q);
                p *= dA;
                w = fmaf(p, cg, w);
            }
        }
        __syncthreads();

        cu0 = nu0; cu1 = nu1; pu0 = np0; pu1 = np1;
    }

    // per-state outputs for recombination
    if (half == 0) H0[(size_t)n*32 + (j & 31)] = h;
    else           W1[(size_t)n*32 + (j & 31)] = w;

    // ---------------- reduce local (q,sk) over the 32-lane seq group ------
    float v0 = fmaf(q, op0[d2], sk0);
    float v1 = fmaf(q, op1[d2], sk1);
#pragma unroll
    for (int m = 16; m >= 1; m >>= 1){
        v0 += __shfl_xor(v0, m, 64);
        v1 += __shfl_xor(v1, m, 64);
    }
    if ((j & 31) == 0){
        QR[(size_t)n*4 + half*2    ] = v0;
        QR[(size_t)n*4 + half*2 + 1] = v1;
    }
}

__global__ void combine_kernel(const float* __restrict__ H0,   // [N,32]
                               const float* __restrict__ W1,   // [N,32]
                               const float* __restrict__ QR,   // [N,2,2]
                               const float* __restrict__ opw,  // [2,4]
                               float* __restrict__ feat)       // [N,2]
{
    const int j   = threadIdx.x;          // 0..255
    const int seq = j >> 5;               // 0..7
    const int k   = j & 31;
    const int d2  = k >> 3;
    const int n   = blockIdx.x * 8 + seq;
    const float val = H0[(size_t)n*32 + k] * W1[(size_t)n*32 + k];
    float v0 = val * opw[d2];
    float v1 = val * opw[4 + d2];
#pragma unroll
    for (int m = 16; m >= 1; m >>= 1){
        v0 += __shfl_xor(v0, m, 64);
        v1 += __shfl_xor(v1, m, 64);
    }
    if (k == 0){
        const float q00 = QR[(size_t)n*4+0], q01 = QR[(size_t)n*4+1];
        const float q10 = QR[(size_t)n*4+2], q11 = QR[(size_t)n*4+3];
        feat[(size_t)n*2    ] = (q00 + q10 + v0) * (1.0f / T_LEN);
        feat[(size_t)n*2 + 1] = (q01 + q11 + v1) * (1.0f / T_LEN);
    }
}

__global__ void proj_kernel(const float* __restrict__ feat,   // [N,2]
                            const float* __restrict__ pw,     // [16,2]
                            const float* __restrict__ pb,     // [16]
                            float* __restrict__ out)          // [8*16*16]
{
    const int tid = blockIdx.x * blockDim.x + threadIdx.x;    // 0..2047
    const int grp = tid >> 4;                                 // b*16+w, 0..127
    const int m   = tid & 15;
    const float w0 = pw[m*2], w1 = pw[m*2+1], b = pb[m];
    const float* f = feat + (size_t)grp * 36 * 2;
    float acc = 0.f;
#pragma unroll
    for (int p = 0; p < 36; ++p){
        float v = fmaf(f[p*2], w0, fmaf(f[p*2+1], w1, b));
        acc += fmaxf(v, 0.f);
    }
    out[tid] = acc * (1.0f / 36.0f);
}

extern "C" void kernel_launch(void* const* d_in, const int* in_sizes, int n_in,
                              void* d_out, int out_size, void* d_ws, size_t ws_size,
                              hipStream_t stream)
{
    (void)in_sizes; (void)n_in; (void)out_size; (void)ws_size;
    const float* raw        = (const float*)d_in[0];
    const float* in_proj_w  = (const float*)d_in[1];
    const float* conv_w     = (const float*)d_in[2];
    const float* conv_b     = (const float*)d_in[3];
    const float* x_proj_w   = (const float*)d_in[4];
    const float* dt_proj_w  = (const float*)d_in[5];
    const float* dt_proj_b  = (const float*)d_in[6];
    const float* A_log      = (const float*)d_in[7];
    const float* D_skip     = (const float*)d_in[8];
    const float* out_proj_w = (const float*)d_in[9];
    const float* proj_w     = (const float*)d_in[10];
    const float* proj_b     = (const float*)d_in[11];

    float* H0   = (float*)d_ws;                 // 4608*32
    float* W1   = H0 + (size_t)N_SEQ*32;        // 4608*32
    float* QR   = W1 + (size_t)N_SEQ*32;        // 4608*4
    float* feat = QR + (size_t)N_SEQ*4;         // 4608*2
    // total ws: 4608*(32+32+4+2)*4 B = 1,290,240 B

    mamba_half_kernel<<<dim3(N_SEQ / SPB, TSPLIT), dim3(64), 0, stream>>>(
        raw, in_proj_w, conv_w, conv_b, x_proj_w, dt_proj_w, dt_proj_b,
        A_log, D_skip, out_proj_w, H0, W1, QR);

    combine_kernel<<<dim3(N_SEQ / 8), dim3(256), 0, stream>>>(H0, W1, QR, out_proj_w, feat);

    proj_kernel<<<dim3(8), dim3(256), 0, stream>>>(feat, proj_w, proj_b, (float*)d_out);
}

// Round 4
// 168.697 us; speedup vs baseline: 1.0032x; 1.0032x over previous
//
#include <hip/hip_runtime.h>

// PairwiseMamba R4: revert time-split (R3 regression). One wave = 2 seqs,
// full T=2048 per block, chunked TC=64 with two front-end passes per chunk.
// LDS record is plane-major so phase 2 reads 2 steps per b128:
//   ddx[seq][d][t]: (dts, dtx) float2, row 66 float2 (pad 2)
//   bc [seq][s][t]: (B, C)    float2, row 66 float2 (pad 2)
//   g  [seq][d][t]: float,    row 66 floats (pad 2)
// Phase 2: lane (seq,d,s), per pair-iteration: 3 LDS reads, 8 VALU, 2 exp2.
// dts = dt*log2(e) (softplus without final LN2 mul), dA = exp2(dts * A),
// A = -exp(A_log) plain. Skip-term deferred to per-lane sgx[d] accumulators.

#define T_LEN  2048
#define N_SEQ  4608
#define SPB    2
#define TC     64
#define NCH    (T_LEN / TC)       // 32
#define LOG2E  1.4426950408889634f
#define LN2    0.6931471805599453f

#define DDX_ROW 132   // floats per (seq,d) ddx row: 64 float2 + 2 pad float2
#define BC_ROW  132   // floats per (seq,s) bc row
#define G_ROW   66    // floats per (seq,d) g row

__device__ __forceinline__ float fexp2(float x){ return __builtin_amdgcn_exp2f(x); }
__device__ __forceinline__ float frcp (float x){ return __builtin_amdgcn_rcpf(x); }
__device__ __forceinline__ float flog2(float x){ return __builtin_amdgcn_logf(x); }
__device__ __forceinline__ float silu_f(float v){ return v * frcp(1.0f + fexp2(v * -LOG2E)); }

__global__ __launch_bounds__(64, 4) void mamba_feat_kernel(
    const float* __restrict__ raw,        // [N,2,T]
    const float* __restrict__ in_proj_w,  // [8,2]
    const float* __restrict__ conv_w,     // [4,2]
    const float* __restrict__ conv_b,     // [4]
    const float* __restrict__ x_proj_w,   // [17,4]
    const float* __restrict__ dt_proj_w,  // [4,1]
    const float* __restrict__ dt_proj_b,  // [4]
    const float* __restrict__ A_log,      // [4,8]
    const float* __restrict__ D_skip,     // [4]
    const float* __restrict__ out_proj_w, // [2,4]
    float* __restrict__ feat)             // [N,2]
{
    __shared__ __attribute__((aligned(16))) float ddxP[SPB * 4 * DDX_ROW]; // 4224 B
    __shared__ __attribute__((aligned(16))) float bcP [SPB * 8 * BC_ROW];  // 8448 B
    __shared__ __attribute__((aligned(16))) float gP  [SPB * 4 * G_ROW];   // 2112 B

    const int j   = threadIdx.x;   // 0..63
    const int seq = j >> 5;        // 0..1 (both roles)
    const int tt  = j & 31;        // phase-1: time slot within pass
    const int d2  = (j & 31) >> 3; // phase-2: inner channel
    const int s2  = j & 7;         // phase-2: state

    // ---------------- weights (wave-uniform -> SGPRs) ----------------
    float wi[8][2];
#pragma unroll
    for (int r = 0; r < 8; ++r){ wi[r][0] = in_proj_w[r*2]; wi[r][1] = in_proj_w[r*2+1]; }
    float cw0[4], cw1[4], cb[4], dtwL[4], dtbL[4], op0[4], op1[4], op0D[4], op1D[4];
#pragma unroll
    for (int d = 0; d < 4; ++d){
        cw0[d] = conv_w[d*2]; cw1[d] = conv_w[d*2+1]; cb[d] = conv_b[d];
        dtwL[d] = dt_proj_w[d] * LOG2E; dtbL[d] = dt_proj_b[d] * LOG2E;
        op0[d] = out_proj_w[d]; op1[d] = out_proj_w[4+d];
        float Dk = D_skip[d];
        op0D[d] = op0[d] * Dk; op1D[d] = op1[d] * Dk;
    }
    float xw[17][4];
#pragma unroll
    for (int r = 0; r < 17; ++r)
#pragma unroll
        for (int d = 0; d < 4; ++d) xw[r][d] = x_proj_w[r*4 + d];
    // per-lane plain A (negative): dA = exp2(dts * Al), dts = dt*log2e
    const float Al = -fexp2(A_log[d2*8 + s2] * LOG2E);

    const int n = blockIdx.x * SPB + seq;
    const float* u0base = raw + (size_t)n * 2 * T_LEN;
    const float* u1base = u0base + T_LEN;

    // phase-1 write bases (float indices)
    const int wdd = seq*4*DDX_ROW;      // + tpos*2 + d*DDX_ROW
    const int wbc = seq*8*BC_ROW;       // + tpos*2 + s*BC_ROW
    const int wg  = seq*4*G_ROW;        // + tpos   + d*G_ROW
    // phase-2 read bases
    const int rdd = seq*4*DDX_ROW + d2*DDX_ROW;  // + tp*4
    const int rbc = seq*8*BC_ROW  + s2*BC_ROW;   // + tp*4
    const int rg  = seq*4*G_ROW   + d2*G_ROW;    // + tp*2

    float h = 0.f, q = 0.f;
    float sgx[4] = {0.f, 0.f, 0.f, 0.f};

    // u staging: [pass] current and next chunk
    float cu0[2], cu1[2], pu0[2], pu1[2];
    float nu0[2], nu1[2], np0[2], np1[2];
#pragma unroll
    for (int p = 0; p < 2; ++p){
        const int t = p*32 + tt;
        cu0[p] = u0base[t];  cu1[p] = u1base[t];
        pu0[p] = (t > 0) ? u0base[t-1] : 0.f;
        pu1[p] = (t > 0) ? u1base[t-1] : 0.f;
    }

    for (int c = 0; c < NCH; ++c){
        // ================= phase 1: two passes of front-end =================
#pragma unroll
        for (int p = 0; p < 2; ++p){
            const float a0 = cu0[p], a1 = cu1[p], b0 = pu0[p], b1 = pu1[p];
            const int tpos = p*32 + tt;
            float x[4], g[4];
#pragma unroll
            for (int d = 0; d < 4; ++d){
                float xr = fmaf(a0, wi[d][0],   a1 * wi[d][1]);
                float xp = fmaf(b0, wi[d][0],   b1 * wi[d][1]);
                float zr = fmaf(a0, wi[4+d][0], a1 * wi[4+d][1]);
                float xc = fmaf(xp, cw0[d], fmaf(xr, cw1[d], cb[d]));
                x[d] = silu_f(xc);
                g[d] = silu_f(zr);
            }
            float dtr = 0.f;
#pragma unroll
            for (int d = 0; d < 4; ++d) dtr = fmaf(x[d], xw[0][d], dtr);
            float Bv[8], Cv[8];
#pragma unroll
            for (int s = 0; s < 8; ++s){
                float b  = x[0] * xw[1+s][0];
                float cc = x[0] * xw[9+s][0];
#pragma unroll
                for (int d = 1; d < 4; ++d){
                    b  = fmaf(x[d], xw[1+s][d], b);
                    cc = fmaf(x[d], xw[9+s][d], cc);
                }
                Bv[s] = b; Cv[s] = cc;
            }
#pragma unroll
            for (int d = 0; d < 4; ++d){
                float vl  = fmaf(dtr, dtwL[d], dtbL[d]);
                float dts = flog2(1.0f + fexp2(vl));     // dt * log2(e)
                float dtx = (LN2 * dts) * x[d];
                *(float2*)&ddxP[wdd + d*DDX_ROW + tpos*2] = make_float2(dts, dtx);
                sgx[d] = fmaf(g[d], x[d], sgx[d]);
                gP[wg + d*G_ROW + tpos] = g[d];
            }
#pragma unroll
            for (int s = 0; s < 8; ++s)
                *(float2*)&bcP[wbc + s*BC_ROW + tpos*2] = make_float2(Bv[s], Cv[s]);
        }
        __syncthreads();

        // prefetch u for next chunk (hides HBM latency under phase 2)
        if (c + 1 < NCH){
#pragma unroll
            for (int p = 0; p < 2; ++p){
                const int t = (c+1)*TC + p*32 + tt;
                nu0[p] = u0base[t];   nu1[p] = u1base[t];
                np0[p] = u0base[t-1]; np1[p] = u1base[t-1];
            }
        }

        // ================= phase 2: 32 pair-iterations (64 steps) ============
#pragma unroll
        for (int tp = 0; tp < TC/2; ++tp){
            const float4 dx = *(const float4*)&ddxP[rdd + tp*4]; // dts0,dtx0,dts1,dtx1
            const float4 bc = *(const float4*)&bcP [rbc + tp*4]; // B0,C0,B1,C1
            const float2 gg = *(const float2*)&gP  [rg  + tp*2]; // g0,g1
            const float dA0 = fexp2(dx.x * Al);
            h = fmaf(dA0, h, dx.y * bc.x);
            q = fmaf(h, bc.y * gg.x, q);
            const float dA1 = fexp2(dx.z * Al);
            h = fmaf(dA1, h, dx.w * bc.z);
            q = fmaf(h, bc.w * gg.y, q);
        }
        __syncthreads();

#pragma unroll
        for (int p = 0; p < 2; ++p){
            cu0[p] = nu0[p]; cu1[p] = nu1[p]; pu0[p] = np0[p]; pu1[p] = np1[p];
        }
    }

    // ---------------- epilogue: fold skip + out_proj, reduce 32 lanes -------
    float v0 = q * op0[d2];
    float v1 = q * op1[d2];
#pragma unroll
    for (int d = 0; d < 4; ++d){
        v0 = fmaf(sgx[d], op0D[d], v0);
        v1 = fmaf(sgx[d], op1D[d], v1);
    }
#pragma unroll
    for (int m = 16; m >= 1; m >>= 1){
        v0 += __shfl_xor(v0, m, 64);
        v1 += __shfl_xor(v1, m, 64);
    }
    if ((j & 31) == 0){
        feat[(size_t)n*2    ] = v0 * (1.0f / T_LEN);
        feat[(size_t)n*2 + 1] = v1 * (1.0f / T_LEN);
    }
}

__global__ void proj_kernel(const float* __restrict__ feat,   // [N,2]
                            const float* __restrict__ pw,     // [16,2]
                            const float* __restrict__ pb,     // [16]
                            float* __restrict__ out)          // [8*16*16]
{
    const int tid = blockIdx.x * blockDim.x + threadIdx.x;    // 0..2047
    const int grp = tid >> 4;                                 // b*16+w, 0..127
    const int m   = tid & 15;
    const float w0 = pw[m*2], w1 = pw[m*2+1], b = pb[m];
    const float* f = feat + (size_t)grp * 36 * 2;
    float acc = 0.f;
#pragma unroll
    for (int p = 0; p < 36; ++p){
        float v = fmaf(f[p*2], w0, fmaf(f[p*2+1], w1, b));
        acc += fmaxf(v, 0.f);
    }
    out[tid] = acc * (1.0f / 36.0f);
}

extern "C" void kernel_launch(void* const* d_in, const int* in_sizes, int n_in,
                              void* d_out, int out_size, void* d_ws, size_t ws_size,
                              hipStream_t stream)
{
    (void)in_sizes; (void)n_in; (void)out_size; (void)ws_size;
    const float* raw        = (const float*)d_in[0];
    const float* in_proj_w  = (const float*)d_in[1];
    const float* conv_w     = (const float*)d_in[2];
    const float* conv_b     = (const float*)d_in[3];
    const float* x_proj_w   = (const float*)d_in[4];
    const float* dt_proj_w  = (const float*)d_in[5];
    const float* dt_proj_b  = (const float*)d_in[6];
    const float* A_log      = (const float*)d_in[7];
    const float* D_skip     = (const float*)d_in[8];
    const float* out_proj_w = (const float*)d_in[9];
    const float* proj_w     = (const float*)d_in[10];
    const float* proj_b     = (const float*)d_in[11];

    float* feat = (float*)d_ws;   // 4608*2 floats

    mamba_feat_kernel<<<dim3(N_SEQ / SPB), dim3(64), 0, stream>>>(
        raw, in_proj_w, conv_w, conv_b, x_proj_w, dt_proj_w, dt_proj_b,
        A_log, D_skip, out_proj_w, feat);

    proj_kernel<<<dim3(8), dim3(256), 0, stream>>>(feat, proj_w, proj_b, (float*)d_out);
}